// Round 3
// baseline (944.802 us; speedup 1.0000x reference)
//
#include <hip/hip_runtime.h>

// LSPD_43404939493531: bidirectional 2-layer GRU (B=512,T=512,U=32) + BN folds + dense head.
// Key algebra: layer-0 input projection = table gather (emb@W+b)[argmax]; inter-layer BN and
// pre-dense BN folded into downstream weight matrices; dense j=0 dead (reference bug).
// R3: exact R1 bodies (known-correct) + __launch_bounds__(64,1) on the GRU kernels only,
//     so the 96 weight VGPRs stay resident (R1 allocated just 80 VGPRs -> per-step reloads).

#define Bsz 512
#define Tsz 512

__device__ __forceinline__ float sigmoid_f(float x) {
    return __builtin_amdgcn_rcpf(1.0f + __expf(-x));
}
__device__ __forceinline__ float bperm_f(int addr, float v) {
    return __int_as_float(__builtin_amdgcn_ds_bpermute(addr, __float_as_int(v)));
}

// ---------------- K1: argmax over D=128, one wave per (b,t), t-fastest ----------------
__global__ __launch_bounds__(256) void lspd_argmax(const float* __restrict__ x, int* __restrict__ idxT)
{
    int wv = threadIdx.x >> 6, lane = threadIdx.x & 63;
    long p = (long)blockIdx.x * 4 + wv;           // p = b*512 + t
    const float* xp = x + p * 128;
    float v0 = xp[lane];      int i0 = lane;
    float v1 = xp[64 + lane]; int i1 = 64 + lane;
    if (v1 > v0) { v0 = v1; i0 = i1; }            // ties keep lower index (first occurrence)
#pragma unroll
    for (int d = 1; d < 64; d <<= 1) {
        float ov = __shfl_xor(v0, d, 64);
        int   oi = __shfl_xor(i0, d, 64);
        if (ov > v0 || (ov == v0 && oi < i0)) { v0 = ov; i0 = oi; }
    }
    if (lane == 0) idxT[p] = i0;
}

// ---------------- K0: layer-0 input tables tab[i][g] = (emb@W0)[i][g] + b0_in[g] ----------------
__global__ __launch_bounds__(256) void lspd_tab(
    const float* __restrict__ emb, const float* __restrict__ Wl, const float* __restrict__ bl,
    const float* __restrict__ Wr, const float* __restrict__ br,
    float* __restrict__ tabL, float* __restrict__ tabR)
{
    int flat = blockIdx.x * 256 + threadIdx.x;    // 0..24575
    int dir = flat / 12288;
    int r = flat % 12288;
    int i = r / 96, g = r % 96;
    const float* W  = dir ? Wr : Wl;              // layer 0 at base
    const float* bb = dir ? br : bl;              // b[0][0] input bias at base
    float acc = bb[g];
#pragma unroll
    for (int k = 0; k < 32; ++k) acc = fmaf(emb[i * 32 + k], W[k * 96 + g], acc);
    (dir ? tabR : tabL)[r] = acc;
}

// ---------------- K2: layer-0 GRU, 1 row per wave64, both directions in one grid ----------------
__global__ __launch_bounds__(64, 1) void lspd_gru0(
    const int* __restrict__ idxT, const float* __restrict__ tabL, const float* __restrict__ tabR,
    const float* __restrict__ Ul, const float* __restrict__ Ur,
    const float* __restrict__ bl, const float* __restrict__ br,
    float* __restrict__ Lout, float* __restrict__ Rout)
{
    int wid = blockIdx.x;
    int dir = wid >> 9;
    int b = wid & 511;
    int lane = threadIdx.x;
    int half = lane >> 5, c = lane & 31;
    const float* U    = dir ? Ur : Ul;
    const float* tab  = dir ? tabR : tabL;
    const float* brec = (dir ? br : bl) + 96;     // layer-0 recurrent bias b[0][1]
    float* out        = dir ? Rout : Lout;

    float u0[16], u1[16], u2[16];
#pragma unroll
    for (int j = 0; j < 16; ++j) {
        int k = half * 16 + j;
        u0[j] = U[k * 96 + c];
        u1[j] = U[k * 96 + 32 + c];
        u2[j] = U[k * 96 + 64 + c];
    }
    float bZ = half ? 0.f : brec[c];
    float bR = half ? 0.f : brec[32 + c];
    float bH = half ? 0.f : brec[64 + c];
    int axor = (lane ^ 32) << 2;
    int hb = half << 6;                            // source lanes half*16 + j

    const int* idxrow = idxT + (long)b * Tsz;
    if (lane < 32) out[(((long)(dir ? Tsz - 1 : 0)) * Bsz + b) * 32 + c] = 0.f;  // boundary zero

    int dt = dir ? -1 : 1;
    int tcur = dir ? Tsz - 2 : 1;
    long ob = ((long)tcur * Bsz + b) * 32 + c;
    long ostride = (long)dt * Bsz * 32;

    int id = idxrow[tcur];
    float giz = tab[id * 96 + c];
    float gir = tab[id * 96 + 32 + c];
    float gih = tab[id * 96 + 64 + c];
    float h = 0.f;

    for (int s = 0; s < Tsz - 1; ++s) {
        float cz = giz, cr = gir, ch = gih;
        // prefetch next step's gi (independent of recurrence chain)
        int tpre = (s < Tsz - 2) ? (tcur + dt) : tcur;
        int id2 = idxrow[tpre];
        giz = tab[id2 * 96 + c];
        gir = tab[id2 * 96 + 32 + c];
        gih = tab[id2 * 96 + 64 + c];

        float az = bZ, ar = bR, ah = bH;
#pragma unroll
        for (int j = 0; j < 16; ++j) {
            float hk = bperm_f(hb + 4 * j, h);
            az = fmaf(hk, u0[j], az);
            ar = fmaf(hk, u1[j], ar);
            ah = fmaf(hk, u2[j], ah);
        }
        az += bperm_f(axor, az);
        ar += bperm_f(axor, ar);
        ah += bperm_f(axor, ah);
        float z = sigmoid_f(az + cz);
        float r = sigmoid_f(ar + cr);
        float hh = fmaxf(0.f, fmaf(r, ah, ch));
        h = hh + z * (h - hh);
        if (lane < 32) out[ob] = h;
        ob += ostride;
        tcur += dt;
    }
}

// ---------------- K3/K5: per-channel sum & sumsq of (L+R) ----------------
__global__ __launch_bounds__(256) void lspd_stats(
    const float* __restrict__ A, const float* __restrict__ Bv, float* __restrict__ part)
{
    __shared__ float sS[256], sQ[256];
    int tid = threadIdx.x;
    size_t base = (size_t)blockIdx.x * 65536 + tid;
    float s = 0.f, q = 0.f;
    for (int i = 0; i < 256; ++i) {
        size_t ix = base + (size_t)i * 256;
        float v = A[ix] + Bv[ix];
        s += v; q = fmaf(v, v, q);
    }
    sS[tid] = s; sQ[tid] = q;
    __syncthreads();
    if (tid < 32) {
        float S = 0.f, Q = 0.f;
        for (int j = 0; j < 8; ++j) { S += sS[tid + 32 * j]; Q += sQ[tid + 32 * j]; }
        part[blockIdx.x * 64 + tid] = S;
        part[blockIdx.x * 64 + 32 + tid] = Q;
    }
}

// ---------------- K3b: fold layer-0 BN into layer-1 input weights ----------------
__global__ __launch_bounds__(256) void lspd_fold1(
    const float* __restrict__ part, const float* __restrict__ g0, const float* __restrict__ be0,
    const float* __restrict__ Wl, const float* __restrict__ Wr,
    const float* __restrict__ bl, const float* __restrict__ br,
    float* __restrict__ WpL, float* __restrict__ WpR,
    float* __restrict__ b4L, float* __restrict__ b4R)
{
    __shared__ float sc[32], tc[32];
    int tid = threadIdx.x;
    if (tid < 32) {
        float S = 0.f, Q = 0.f;
        for (int p = 0; p < 128; ++p) { S += part[p * 64 + tid]; Q += part[p * 64 + 32 + tid]; }
        const float invN = 1.0f / 262144.0f;
        float m = S * invN;
        float v = Q * invN - m * m;
        float s = g0[tid] * __builtin_amdgcn_rsqf(v + 1e-3f);
        sc[tid] = s; tc[tid] = be0[tid] - s * m;
    }
    __syncthreads();
    for (int idx = tid; idx < 6144; idx += 256) {
        int dir = idx / 3072, e = idx % 3072, k = e / 96, g = e % 96;
        const float* W1 = (dir ? Wr : Wl) + 3072;      // layer 1
        (dir ? WpR : WpL)[e] = sc[k] * W1[k * 96 + g];
    }
    {
        int idx = tid;                                  // 256 entries exactly
        int dir = idx >> 7, slot = idx & 127, sub = slot >> 5, cc = slot & 31;
        const float* bb = (dir ? br : bl) + 192;        // layer-1: [0..95]=input, [96..191]=recurrent
        const float* W1 = (dir ? Wr : Wl) + 3072;
        float r;
        if (sub == 2) {
            r = bb[96 + 64 + cc];                       // rh: recurrent h-bias only
        } else {
            int g = (sub == 3) ? (64 + cc) : (sub * 32 + cc);
            float acc = bb[g];                          // input bias
            for (int k = 0; k < 32; ++k) acc = fmaf(tc[k], W1[k * 96 + g], acc);
            if (sub < 2) acc += bb[96 + g];             // z,r: + recurrent bias
            r = acc;
        }
        (dir ? b4R : b4L)[slot] = r;
    }
}

// ---------------- K4: layer-1 GRU with on-the-fly folded input projection ----------------
__global__ __launch_bounds__(64, 1) void lspd_gru1(
    const float* __restrict__ L0, const float* __restrict__ R0,
    const float* __restrict__ WpL, const float* __restrict__ WpR,
    const float* __restrict__ b4L, const float* __restrict__ b4R,
    const float* __restrict__ Ul1, const float* __restrict__ Ur1,
    float* __restrict__ Lout, float* __restrict__ Rout)
{
    int wid = blockIdx.x;
    int dir = wid >> 9;
    int b = wid & 511;
    int lane = threadIdx.x;
    int half = lane >> 5, c = lane & 31;
    const float* U  = dir ? Ur1 : Ul1;
    const float* Wp = dir ? WpR : WpL;
    const float* b4 = dir ? b4R : b4L;
    float* out      = dir ? Rout : Lout;

    float u0[16], u1[16], u2[16], w0[16], w1[16], w2[16];
#pragma unroll
    for (int j = 0; j < 16; ++j) {
        int k = half * 16 + j;
        u0[j] = U[k * 96 + c];
        u1[j] = U[k * 96 + 32 + c];
        u2[j] = U[k * 96 + 64 + c];
        w0[j] = Wp[k * 96 + c];
        w1[j] = Wp[k * 96 + 32 + c];
        w2[j] = Wp[k * 96 + 64 + c];
    }
    float bZ = half ? 0.f : b4[c];
    float bR = half ? 0.f : b4[32 + c];
    float bH = half ? 0.f : b4[64 + c];   // recurrent-h bias
    float bI = half ? 0.f : b4[96 + c];   // input-h bias (folded)
    int axor = (lane ^ 32) << 2;
    int hb = half << 6;

    if (lane < 32) out[(((long)(dir ? Tsz - 1 : 0)) * Bsz + b) * 32 + c] = 0.f;

    int dt = dir ? -1 : 1;
    int tcur = dir ? Tsz - 2 : 1;
    long rb = ((long)tcur * Bsz + b) * 32 + c;
    long stride = (long)dt * Bsz * 32;

    float xl = L0[rb], xr = R0[rb];
    float h = 0.f;
    for (int s = 0; s < Tsz - 1; ++s) {
        float x = xl + xr;
        long rbn = rb + ((s < Tsz - 2) ? stride : 0);
        xl = L0[rbn]; xr = R0[rbn];                 // prefetch next step's input

        float az = bZ, ar = bR, ah = bH, ai = bI;
#pragma unroll
        for (int j = 0; j < 16; ++j) {
            float xk = bperm_f(hb + 4 * j, x);
            az = fmaf(xk, w0[j], az);
            ar = fmaf(xk, w1[j], ar);
            ai = fmaf(xk, w2[j], ai);
        }
#pragma unroll
        for (int j = 0; j < 16; ++j) {
            float hk = bperm_f(hb + 4 * j, h);
            az = fmaf(hk, u0[j], az);
            ar = fmaf(hk, u1[j], ar);
            ah = fmaf(hk, u2[j], ah);
        }
        az += bperm_f(axor, az);
        ar += bperm_f(axor, ar);
        ah += bperm_f(axor, ah);
        ai += bperm_f(axor, ai);
        float z = sigmoid_f(az);
        float r = sigmoid_f(ar);
        float hh = fmaxf(0.f, fmaf(r, ah, ai));
        h = hh + z * (h - hh);
        if (lane < 32) out[rb] = h;
        rb = rbn;
    }
}

// ---------------- K5b: fold layer-1 BN into dense-1 weights ----------------
__global__ __launch_bounds__(256) void lspd_fold2(
    const float* __restrict__ part, const float* __restrict__ g1, const float* __restrict__ be1,
    const float* __restrict__ Wd1, const float* __restrict__ bd1,
    float* __restrict__ Wdp, float* __restrict__ bdp)
{
    __shared__ float sc[32], tc[32];
    int tid = threadIdx.x;
    if (tid < 32) {
        float S = 0.f, Q = 0.f;
        for (int p = 0; p < 128; ++p) { S += part[p * 64 + tid]; Q += part[p * 64 + 32 + tid]; }
        const float invN = 1.0f / 262144.0f;
        float m = S * invN;
        float v = Q * invN - m * m;
        float s = g1[tid] * __builtin_amdgcn_rsqf(v + 1e-3f);
        sc[tid] = s; tc[tid] = be1[tid] - s * m;
    }
    __syncthreads();
    for (int idx = tid; idx < 1024; idx += 256) {
        int k = idx >> 5;
        Wdp[idx] = sc[k] * Wd1[idx];
    }
    if (tid < 32) {
        float acc = bd1[tid];
        for (int k = 0; k < 32; ++k) acc = fmaf(tc[k], Wd1[k * 32 + tid], acc);
        bdp[tid] = acc;
    }
}

// ---------------- K6: dense + per-t batch BN + classifier + softmax; one block per t ----------------
__global__ __launch_bounds__(512) void lspd_final(
    const float* __restrict__ L1a, const float* __restrict__ R1a,
    const float* __restrict__ Wdp, const float* __restrict__ bdp,
    const float* __restrict__ dg, const float* __restrict__ db,
    const float* __restrict__ Wf, const float* __restrict__ bfv,
    float* __restrict__ outp)
{
    __shared__ alignas(16) float sW[1024];
    __shared__ float sb[32], sWf[352], sbf[16], sS[32], sT[32];
    __shared__ float redS[8][32], redQ[8][32];
    int tid = threadIdx.x, t = blockIdx.x;
    for (int i = tid; i < 1024; i += 512) sW[i] = Wdp[i];
    if (tid < 32)  sb[tid] = bdp[tid];
    if (tid < 352) sWf[tid] = Wf[tid];
    if (tid < 11)  sbf[tid] = bfv[tid];
    __syncthreads();

    size_t base = ((size_t)t * Bsz + tid) * 32;
    float xv[32];
#pragma unroll
    for (int c2 = 0; c2 < 32; c2 += 4) {
        float4 a = *(const float4*)(L1a + base + c2);
        float4 b = *(const float4*)(R1a + base + c2);
        xv[c2 + 0] = a.x + b.x; xv[c2 + 1] = a.y + b.y;
        xv[c2 + 2] = a.z + b.z; xv[c2 + 3] = a.w + b.w;
    }
    float o[32];
#pragma unroll
    for (int g = 0; g < 32; ++g) o[g] = sb[g];
#pragma unroll
    for (int k = 0; k < 32; ++k) {
        float xk = xv[k];
#pragma unroll
        for (int g4 = 0; g4 < 8; ++g4) {
            float4 w = *(const float4*)(sW + k * 32 + g4 * 4);   // same-address LDS broadcast
            o[g4 * 4 + 0] = fmaf(xk, w.x, o[g4 * 4 + 0]);
            o[g4 * 4 + 1] = fmaf(xk, w.y, o[g4 * 4 + 1]);
            o[g4 * 4 + 2] = fmaf(xk, w.z, o[g4 * 4 + 2]);
            o[g4 * 4 + 3] = fmaf(xk, w.w, o[g4 * 4 + 3]);
        }
    }
#pragma unroll
    for (int g = 0; g < 32; ++g) o[g] = fmaxf(o[g], 0.f);

    // per-(t,channel) stats over batch (within block)
    int wv = tid >> 6, lane = tid & 63;
    for (int g = 0; g < 32; ++g) {
        float s = o[g], q = o[g] * o[g];
        for (int d = 1; d < 64; d <<= 1) {
            s += __shfl_xor(s, d, 64);
            q += __shfl_xor(q, d, 64);
        }
        if (lane == 0) { redS[wv][g] = s; redQ[wv][g] = q; }
    }
    __syncthreads();
    if (tid < 32) {
        float S = 0.f, Q = 0.f;
        for (int w2 = 0; w2 < 8; ++w2) { S += redS[w2][tid]; Q += redQ[w2][tid]; }
        float m = S * (1.0f / 512.0f);
        float v = Q * (1.0f / 512.0f) - m * m;
        float s = dg[tid] * __builtin_amdgcn_rsqf(v + 1e-3f);
        sS[tid] = s; sT[tid] = db[tid] - s * m;
    }
    __syncthreads();

    float lg[11];
#pragma unroll
    for (int n = 0; n < 11; ++n) lg[n] = sbf[n];
#pragma unroll
    for (int g = 0; g < 32; ++g) {
        float no = fmaf(o[g], sS[g], sT[g]);
#pragma unroll
        for (int n = 0; n < 11; ++n) lg[n] = fmaf(no, sWf[g * 11 + n], lg[n]);
    }
    float mx = lg[0];
#pragma unroll
    for (int n = 1; n < 11; ++n) mx = fmaxf(mx, lg[n]);
    float sum = 0.f;
#pragma unroll
    for (int n = 0; n < 11; ++n) { lg[n] = __expf(lg[n] - mx); sum += lg[n]; }
    float inv = __builtin_amdgcn_rcpf(sum);
    float* op = outp + ((size_t)tid * Tsz + t) * 11;
#pragma unroll
    for (int n = 0; n < 11; ++n) op[n] = lg[n] * inv;
}

extern "C" void kernel_launch(void* const* d_in, const int* in_sizes, int n_in,
                              void* d_out, int out_size, void* d_ws, size_t ws_size,
                              hipStream_t stream)
{
    (void)in_sizes; (void)n_in; (void)out_size; (void)ws_size;
    const float* x   = (const float*)d_in[0];
    const float* emb = (const float*)d_in[1];
    const float* Wl  = (const float*)d_in[2];
    const float* Ul  = (const float*)d_in[3];
    const float* bl  = (const float*)d_in[4];
    const float* Wr  = (const float*)d_in[5];
    const float* Ur  = (const float*)d_in[6];
    const float* br  = (const float*)d_in[7];
    const float* bng = (const float*)d_in[8];
    const float* bnb = (const float*)d_in[9];
    const float* Wd  = (const float*)d_in[10];
    const float* bd  = (const float*)d_in[11];
    const float* dg  = (const float*)d_in[12];
    const float* db  = (const float*)d_in[13];
    const float* Wf  = (const float*)d_in[14];
    const float* bf  = (const float*)d_in[15];
    float* out = (float*)d_out;

    float* ws = (float*)d_ws;
    float* L0 = ws;
    float* R0 = L0 + 8388608;
    float* L1 = R0 + 8388608;
    float* R1 = L1 + 8388608;
    float* rest = R1 + 8388608;
    int* idxT   = (int*)rest;            // 262144 ints
    float* tabL = rest + 262144;
    float* tabR = tabL + 12288;
    float* part1 = tabR + 12288;         // 8192
    float* part2 = part1 + 8192;         // 8192
    float* WpL = part2 + 8192;           // 3072
    float* WpR = WpL + 3072;
    float* b4L = WpR + 3072;             // 128
    float* b4R = b4L + 128;
    float* Wdp = b4R + 128;              // 1024
    float* bdp = Wdp + 1024;             // 32

    lspd_argmax<<<65536, 256, 0, stream>>>(x, idxT);
    lspd_tab<<<96, 256, 0, stream>>>(emb, Wl, bl, Wr, br, tabL, tabR);
    lspd_gru0<<<1024, 64, 0, stream>>>(idxT, tabL, tabR, Ul, Ur, bl, br, L0, R0);
    lspd_stats<<<128, 256, 0, stream>>>(L0, R0, part1);
    lspd_fold1<<<1, 256, 0, stream>>>(part1, bng, bnb, Wl, Wr, bl, br, WpL, WpR, b4L, b4R);
    lspd_gru1<<<1024, 64, 0, stream>>>(L0, R0, WpL, WpR, b4L, b4R, Ul + 3072, Ur + 3072, L1, R1);
    lspd_stats<<<128, 256, 0, stream>>>(L1, R1, part2);
    lspd_fold2<<<1, 256, 0, stream>>>(part2, bng + 32, bnb + 32, Wd + 1024, bd + 32, Wdp, bdp);
    lspd_final<<<512, 512, 0, stream>>>(L1, R1, Wdp, bdp, dg + 32, db + 32, Wf, bf, out);
}

// Round 4
// 941.439 us; speedup vs baseline: 1.0036x; 1.0036x over previous
//
#include <hip/hip_runtime.h>

// LSPD_43404939493531: bidirectional 2-layer GRU (B=512,T=512,U=32) + BN folds + dense head.
// Key algebra: layer-0 input projection = table gather (emb@W+b)[argmax]; inter-layer BN and
// pre-dense BN folded into downstream weight matrices; dense j=0 dead (reference bug).
// R4: R3 bodies + empty inline-asm "register pin" on the per-lane weight arrays so the compiler
//     cannot sink/rematerialize the weight loads into the 511-step loop (R3 evidence: VGPR=80
//     despite launch_bounds(64,1) => ~185 extra VALU instrs/step from per-step weight reloads).

#define Bsz 512
#define Tsz 512

__device__ __forceinline__ float sigmoid_f(float x) {
    return __builtin_amdgcn_rcpf(1.0f + __expf(-x));
}
__device__ __forceinline__ float bperm_f(int addr, float v) {
    return __int_as_float(__builtin_amdgcn_ds_bpermute(addr, __float_as_int(v)));
}

// ---------------- K1: argmax over D=128, one wave per (b,t), t-fastest ----------------
__global__ __launch_bounds__(256) void lspd_argmax(const float* __restrict__ x, int* __restrict__ idxT)
{
    int wv = threadIdx.x >> 6, lane = threadIdx.x & 63;
    long p = (long)blockIdx.x * 4 + wv;           // p = b*512 + t
    const float* xp = x + p * 128;
    float v0 = xp[lane];      int i0 = lane;
    float v1 = xp[64 + lane]; int i1 = 64 + lane;
    if (v1 > v0) { v0 = v1; i0 = i1; }            // ties keep lower index (first occurrence)
#pragma unroll
    for (int d = 1; d < 64; d <<= 1) {
        float ov = __shfl_xor(v0, d, 64);
        int   oi = __shfl_xor(i0, d, 64);
        if (ov > v0 || (ov == v0 && oi < i0)) { v0 = ov; i0 = oi; }
    }
    if (lane == 0) idxT[p] = i0;
}

// ---------------- K0: layer-0 input tables tab[i][g] = (emb@W0)[i][g] + b0_in[g] ----------------
__global__ __launch_bounds__(256) void lspd_tab(
    const float* __restrict__ emb, const float* __restrict__ Wl, const float* __restrict__ bl,
    const float* __restrict__ Wr, const float* __restrict__ br,
    float* __restrict__ tabL, float* __restrict__ tabR)
{
    int flat = blockIdx.x * 256 + threadIdx.x;    // 0..24575
    int dir = flat / 12288;
    int r = flat % 12288;
    int i = r / 96, g = r % 96;
    const float* W  = dir ? Wr : Wl;              // layer 0 at base
    const float* bb = dir ? br : bl;              // b[0][0] input bias at base
    float acc = bb[g];
#pragma unroll
    for (int k = 0; k < 32; ++k) acc = fmaf(emb[i * 32 + k], W[k * 96 + g], acc);
    (dir ? tabR : tabL)[r] = acc;
}

// ---------------- K2: layer-0 GRU, 1 row per wave64, both directions in one grid ----------------
__global__ __launch_bounds__(64, 1) void lspd_gru0(
    const int* __restrict__ idxT, const float* __restrict__ tabL, const float* __restrict__ tabR,
    const float* __restrict__ Ul, const float* __restrict__ Ur,
    const float* __restrict__ bl, const float* __restrict__ br,
    float* __restrict__ Lout, float* __restrict__ Rout)
{
    int wid = blockIdx.x;
    int dir = wid >> 9;
    int b = wid & 511;
    int lane = threadIdx.x;
    int half = lane >> 5, c = lane & 31;
    const float* U    = dir ? Ur : Ul;
    const float* tab  = dir ? tabR : tabL;
    const float* brec = (dir ? br : bl) + 96;     // layer-0 recurrent bias b[0][1]
    float* out        = dir ? Rout : Lout;

    float u0[16], u1[16], u2[16];
#pragma unroll
    for (int j = 0; j < 16; ++j) {
        int k = half * 16 + j;
        u0[j] = U[k * 96 + c];
        u1[j] = U[k * 96 + 32 + c];
        u2[j] = U[k * 96 + 64 + c];
    }
    float bZ = half ? 0.f : brec[c];
    float bR = half ? 0.f : brec[32 + c];
    float bH = half ? 0.f : brec[64 + c];
    // Pin weights/biases in VGPRs: opaque to the compiler => cannot be rematerialized in-loop.
#pragma unroll
    for (int j = 0; j < 16; ++j) {
        asm volatile("" : "+v"(u0[j]), "+v"(u1[j]), "+v"(u2[j]));
    }
    asm volatile("" : "+v"(bZ), "+v"(bR), "+v"(bH));
    int axor = (lane ^ 32) << 2;
    int hb = half << 6;                            // source lanes half*16 + j

    const int* idxrow = idxT + (long)b * Tsz;
    if (lane < 32) out[(((long)(dir ? Tsz - 1 : 0)) * Bsz + b) * 32 + c] = 0.f;  // boundary zero

    int dt = dir ? -1 : 1;
    int tcur = dir ? Tsz - 2 : 1;
    long ob = ((long)tcur * Bsz + b) * 32 + c;
    long ostride = (long)dt * Bsz * 32;

    int id = idxrow[tcur];
    float giz = tab[id * 96 + c];
    float gir = tab[id * 96 + 32 + c];
    float gih = tab[id * 96 + 64 + c];
    float h = 0.f;

    for (int s = 0; s < Tsz - 1; ++s) {
        float cz = giz, cr = gir, ch = gih;
        // prefetch next step's gi (independent of recurrence chain)
        int tpre = (s < Tsz - 2) ? (tcur + dt) : tcur;
        int id2 = idxrow[tpre];
        giz = tab[id2 * 96 + c];
        gir = tab[id2 * 96 + 32 + c];
        gih = tab[id2 * 96 + 64 + c];

        float az = bZ, ar = bR, ah = bH;
#pragma unroll
        for (int j = 0; j < 16; ++j) {
            float hk = bperm_f(hb + 4 * j, h);
            az = fmaf(hk, u0[j], az);
            ar = fmaf(hk, u1[j], ar);
            ah = fmaf(hk, u2[j], ah);
        }
        az += bperm_f(axor, az);
        ar += bperm_f(axor, ar);
        ah += bperm_f(axor, ah);
        float z = sigmoid_f(az + cz);
        float r = sigmoid_f(ar + cr);
        float hh = fmaxf(0.f, fmaf(r, ah, ch));
        h = hh + z * (h - hh);
        if (lane < 32) out[ob] = h;
        ob += ostride;
        tcur += dt;
    }
}

// ---------------- K3/K5: per-channel sum & sumsq of (L+R) ----------------
__global__ __launch_bounds__(256) void lspd_stats(
    const float* __restrict__ A, const float* __restrict__ Bv, float* __restrict__ part)
{
    __shared__ float sS[256], sQ[256];
    int tid = threadIdx.x;
    size_t base = (size_t)blockIdx.x * 65536 + tid;
    float s = 0.f, q = 0.f;
    for (int i = 0; i < 256; ++i) {
        size_t ix = base + (size_t)i * 256;
        float v = A[ix] + Bv[ix];
        s += v; q = fmaf(v, v, q);
    }
    sS[tid] = s; sQ[tid] = q;
    __syncthreads();
    if (tid < 32) {
        float S = 0.f, Q = 0.f;
        for (int j = 0; j < 8; ++j) { S += sS[tid + 32 * j]; Q += sQ[tid + 32 * j]; }
        part[blockIdx.x * 64 + tid] = S;
        part[blockIdx.x * 64 + 32 + tid] = Q;
    }
}

// ---------------- K3b: fold layer-0 BN into layer-1 input weights ----------------
__global__ __launch_bounds__(256) void lspd_fold1(
    const float* __restrict__ part, const float* __restrict__ g0, const float* __restrict__ be0,
    const float* __restrict__ Wl, const float* __restrict__ Wr,
    const float* __restrict__ bl, const float* __restrict__ br,
    float* __restrict__ WpL, float* __restrict__ WpR,
    float* __restrict__ b4L, float* __restrict__ b4R)
{
    __shared__ float sc[32], tc[32];
    int tid = threadIdx.x;
    if (tid < 32) {
        float S = 0.f, Q = 0.f;
        for (int p = 0; p < 128; ++p) { S += part[p * 64 + tid]; Q += part[p * 64 + 32 + tid]; }
        const float invN = 1.0f / 262144.0f;
        float m = S * invN;
        float v = Q * invN - m * m;
        float s = g0[tid] * __builtin_amdgcn_rsqf(v + 1e-3f);
        sc[tid] = s; tc[tid] = be0[tid] - s * m;
    }
    __syncthreads();
    for (int idx = tid; idx < 6144; idx += 256) {
        int dir = idx / 3072, e = idx % 3072, k = e / 96, g = e % 96;
        const float* W1 = (dir ? Wr : Wl) + 3072;      // layer 1
        (dir ? WpR : WpL)[e] = sc[k] * W1[k * 96 + g];
    }
    {
        int idx = tid;                                  // 256 entries exactly
        int dir = idx >> 7, slot = idx & 127, sub = slot >> 5, cc = slot & 31;
        const float* bb = (dir ? br : bl) + 192;        // layer-1: [0..95]=input, [96..191]=recurrent
        const float* W1 = (dir ? Wr : Wl) + 3072;
        float r;
        if (sub == 2) {
            r = bb[96 + 64 + cc];                       // rh: recurrent h-bias only
        } else {
            int g = (sub == 3) ? (64 + cc) : (sub * 32 + cc);
            float acc = bb[g];                          // input bias
            for (int k = 0; k < 32; ++k) acc = fmaf(tc[k], W1[k * 96 + g], acc);
            if (sub < 2) acc += bb[96 + g];             // z,r: + recurrent bias
            r = acc;
        }
        (dir ? b4R : b4L)[slot] = r;
    }
}

// ---------------- K4: layer-1 GRU with on-the-fly folded input projection ----------------
__global__ __launch_bounds__(64, 1) void lspd_gru1(
    const float* __restrict__ L0, const float* __restrict__ R0,
    const float* __restrict__ WpL, const float* __restrict__ WpR,
    const float* __restrict__ b4L, const float* __restrict__ b4R,
    const float* __restrict__ Ul1, const float* __restrict__ Ur1,
    float* __restrict__ Lout, float* __restrict__ Rout)
{
    int wid = blockIdx.x;
    int dir = wid >> 9;
    int b = wid & 511;
    int lane = threadIdx.x;
    int half = lane >> 5, c = lane & 31;
    const float* U  = dir ? Ur1 : Ul1;
    const float* Wp = dir ? WpR : WpL;
    const float* b4 = dir ? b4R : b4L;
    float* out      = dir ? Rout : Lout;

    float u0[16], u1[16], u2[16], w0[16], w1[16], w2[16];
#pragma unroll
    for (int j = 0; j < 16; ++j) {
        int k = half * 16 + j;
        u0[j] = U[k * 96 + c];
        u1[j] = U[k * 96 + 32 + c];
        u2[j] = U[k * 96 + 64 + c];
        w0[j] = Wp[k * 96 + c];
        w1[j] = Wp[k * 96 + 32 + c];
        w2[j] = Wp[k * 96 + 64 + c];
    }
    float bZ = half ? 0.f : b4[c];
    float bR = half ? 0.f : b4[32 + c];
    float bH = half ? 0.f : b4[64 + c];   // recurrent-h bias
    float bI = half ? 0.f : b4[96 + c];   // input-h bias (folded)
    // Pin weights/biases in VGPRs (see R4 note at top).
#pragma unroll
    for (int j = 0; j < 16; ++j) {
        asm volatile("" : "+v"(u0[j]), "+v"(u1[j]), "+v"(u2[j]));
        asm volatile("" : "+v"(w0[j]), "+v"(w1[j]), "+v"(w2[j]));
    }
    asm volatile("" : "+v"(bZ), "+v"(bR), "+v"(bH), "+v"(bI));
    int axor = (lane ^ 32) << 2;
    int hb = half << 6;

    if (lane < 32) out[(((long)(dir ? Tsz - 1 : 0)) * Bsz + b) * 32 + c] = 0.f;

    int dt = dir ? -1 : 1;
    int tcur = dir ? Tsz - 2 : 1;
    long rb = ((long)tcur * Bsz + b) * 32 + c;
    long stride = (long)dt * Bsz * 32;

    float xl = L0[rb], xr = R0[rb];
    float h = 0.f;
    for (int s = 0; s < Tsz - 1; ++s) {
        float x = xl + xr;
        long rbn = rb + ((s < Tsz - 2) ? stride : 0);
        xl = L0[rbn]; xr = R0[rbn];                 // prefetch next step's input

        float az = bZ, ar = bR, ah = bH, ai = bI;
#pragma unroll
        for (int j = 0; j < 16; ++j) {
            float xk = bperm_f(hb + 4 * j, x);
            az = fmaf(xk, w0[j], az);
            ar = fmaf(xk, w1[j], ar);
            ai = fmaf(xk, w2[j], ai);
        }
#pragma unroll
        for (int j = 0; j < 16; ++j) {
            float hk = bperm_f(hb + 4 * j, h);
            az = fmaf(hk, u0[j], az);
            ar = fmaf(hk, u1[j], ar);
            ah = fmaf(hk, u2[j], ah);
        }
        az += bperm_f(axor, az);
        ar += bperm_f(axor, ar);
        ah += bperm_f(axor, ah);
        ai += bperm_f(axor, ai);
        float z = sigmoid_f(az);
        float r = sigmoid_f(ar);
        float hh = fmaxf(0.f, fmaf(r, ah, ai));
        h = hh + z * (h - hh);
        if (lane < 32) out[rb] = h;
        rb = rbn;
    }
}

// ---------------- K5b: fold layer-1 BN into dense-1 weights ----------------
__global__ __launch_bounds__(256) void lspd_fold2(
    const float* __restrict__ part, const float* __restrict__ g1, const float* __restrict__ be1,
    const float* __restrict__ Wd1, const float* __restrict__ bd1,
    float* __restrict__ Wdp, float* __restrict__ bdp)
{
    __shared__ float sc[32], tc[32];
    int tid = threadIdx.x;
    if (tid < 32) {
        float S = 0.f, Q = 0.f;
        for (int p = 0; p < 128; ++p) { S += part[p * 64 + tid]; Q += part[p * 64 + 32 + tid]; }
        const float invN = 1.0f / 262144.0f;
        float m = S * invN;
        float v = Q * invN - m * m;
        float s = g1[tid] * __builtin_amdgcn_rsqf(v + 1e-3f);
        sc[tid] = s; tc[tid] = be1[tid] - s * m;
    }
    __syncthreads();
    for (int idx = tid; idx < 1024; idx += 256) {
        int k = idx >> 5;
        Wdp[idx] = sc[k] * Wd1[idx];
    }
    if (tid < 32) {
        float acc = bd1[tid];
        for (int k = 0; k < 32; ++k) acc = fmaf(tc[k], Wd1[k * 32 + tid], acc);
        bdp[tid] = acc;
    }
}

// ---------------- K6: dense + per-t batch BN + classifier + softmax; one block per t ----------------
__global__ __launch_bounds__(512) void lspd_final(
    const float* __restrict__ L1a, const float* __restrict__ R1a,
    const float* __restrict__ Wdp, const float* __restrict__ bdp,
    const float* __restrict__ dg, const float* __restrict__ db,
    const float* __restrict__ Wf, const float* __restrict__ bfv,
    float* __restrict__ outp)
{
    __shared__ alignas(16) float sW[1024];
    __shared__ float sb[32], sWf[352], sbf[16], sS[32], sT[32];
    __shared__ float redS[8][32], redQ[8][32];
    int tid = threadIdx.x, t = blockIdx.x;
    for (int i = tid; i < 1024; i += 512) sW[i] = Wdp[i];
    if (tid < 32)  sb[tid] = bdp[tid];
    if (tid < 352) sWf[tid] = Wf[tid];
    if (tid < 11)  sbf[tid] = bfv[tid];
    __syncthreads();

    size_t base = ((size_t)t * Bsz + tid) * 32;
    float xv[32];
#pragma unroll
    for (int c2 = 0; c2 < 32; c2 += 4) {
        float4 a = *(const float4*)(L1a + base + c2);
        float4 b = *(const float4*)(R1a + base + c2);
        xv[c2 + 0] = a.x + b.x; xv[c2 + 1] = a.y + b.y;
        xv[c2 + 2] = a.z + b.z; xv[c2 + 3] = a.w + b.w;
    }
    float o[32];
#pragma unroll
    for (int g = 0; g < 32; ++g) o[g] = sb[g];
#pragma unroll
    for (int k = 0; k < 32; ++k) {
        float xk = xv[k];
#pragma unroll
        for (int g4 = 0; g4 < 8; ++g4) {
            float4 w = *(const float4*)(sW + k * 32 + g4 * 4);   // same-address LDS broadcast
            o[g4 * 4 + 0] = fmaf(xk, w.x, o[g4 * 4 + 0]);
            o[g4 * 4 + 1] = fmaf(xk, w.y, o[g4 * 4 + 1]);
            o[g4 * 4 + 2] = fmaf(xk, w.z, o[g4 * 4 + 2]);
            o[g4 * 4 + 3] = fmaf(xk, w.w, o[g4 * 4 + 3]);
        }
    }
#pragma unroll
    for (int g = 0; g < 32; ++g) o[g] = fmaxf(o[g], 0.f);

    // per-(t,channel) stats over batch (within block)
    int wv = tid >> 6, lane = tid & 63;
    for (int g = 0; g < 32; ++g) {
        float s = o[g], q = o[g] * o[g];
        for (int d = 1; d < 64; d <<= 1) {
            s += __shfl_xor(s, d, 64);
            q += __shfl_xor(q, d, 64);
        }
        if (lane == 0) { redS[wv][g] = s; redQ[wv][g] = q; }
    }
    __syncthreads();
    if (tid < 32) {
        float S = 0.f, Q = 0.f;
        for (int w2 = 0; w2 < 8; ++w2) { S += redS[w2][tid]; Q += redQ[w2][tid]; }
        float m = S * (1.0f / 512.0f);
        float v = Q * (1.0f / 512.0f) - m * m;
        float s = dg[tid] * __builtin_amdgcn_rsqf(v + 1e-3f);
        sS[tid] = s; sT[tid] = db[tid] - s * m;
    }
    __syncthreads();

    float lg[11];
#pragma unroll
    for (int n = 0; n < 11; ++n) lg[n] = sbf[n];
#pragma unroll
    for (int g = 0; g < 32; ++g) {
        float no = fmaf(o[g], sS[g], sT[g]);
#pragma unroll
        for (int n = 0; n < 11; ++n) lg[n] = fmaf(no, sWf[g * 11 + n], lg[n]);
    }
    float mx = lg[0];
#pragma unroll
    for (int n = 1; n < 11; ++n) mx = fmaxf(mx, lg[n]);
    float sum = 0.f;
#pragma unroll
    for (int n = 0; n < 11; ++n) { lg[n] = __expf(lg[n] - mx); sum += lg[n]; }
    float inv = __builtin_amdgcn_rcpf(sum);
    float* op = outp + ((size_t)tid * Tsz + t) * 11;
#pragma unroll
    for (int n = 0; n < 11; ++n) op[n] = lg[n] * inv;
}

extern "C" void kernel_launch(void* const* d_in, const int* in_sizes, int n_in,
                              void* d_out, int out_size, void* d_ws, size_t ws_size,
                              hipStream_t stream)
{
    (void)in_sizes; (void)n_in; (void)out_size; (void)ws_size;
    const float* x   = (const float*)d_in[0];
    const float* emb = (const float*)d_in[1];
    const float* Wl  = (const float*)d_in[2];
    const float* Ul  = (const float*)d_in[3];
    const float* bl  = (const float*)d_in[4];
    const float* Wr  = (const float*)d_in[5];
    const float* Ur  = (const float*)d_in[6];
    const float* br  = (const float*)d_in[7];
    const float* bng = (const float*)d_in[8];
    const float* bnb = (const float*)d_in[9];
    const float* Wd  = (const float*)d_in[10];
    const float* bd  = (const float*)d_in[11];
    const float* dg  = (const float*)d_in[12];
    const float* db  = (const float*)d_in[13];
    const float* Wf  = (const float*)d_in[14];
    const float* bf  = (const float*)d_in[15];
    float* out = (float*)d_out;

    float* ws = (float*)d_ws;
    float* L0 = ws;
    float* R0 = L0 + 8388608;
    float* L1 = R0 + 8388608;
    float* R1 = L1 + 8388608;
    float* rest = R1 + 8388608;
    int* idxT   = (int*)rest;            // 262144 ints
    float* tabL = rest + 262144;
    float* tabR = tabL + 12288;
    float* part1 = tabR + 12288;         // 8192
    float* part2 = part1 + 8192;         // 8192
    float* WpL = part2 + 8192;           // 3072
    float* WpR = WpL + 3072;
    float* b4L = WpR + 3072;             // 128
    float* b4R = b4L + 128;
    float* Wdp = b4R + 128;              // 1024
    float* bdp = Wdp + 1024;             // 32

    lspd_argmax<<<65536, 256, 0, stream>>>(x, idxT);
    lspd_tab<<<96, 256, 0, stream>>>(emb, Wl, bl, Wr, br, tabL, tabR);
    lspd_gru0<<<1024, 64, 0, stream>>>(idxT, tabL, tabR, Ul, Ur, bl, br, L0, R0);
    lspd_stats<<<128, 256, 0, stream>>>(L0, R0, part1);
    lspd_fold1<<<1, 256, 0, stream>>>(part1, bng, bnb, Wl, Wr, bl, br, WpL, WpR, b4L, b4R);
    lspd_gru1<<<1024, 64, 0, stream>>>(L0, R0, WpL, WpR, b4L, b4R, Ul + 3072, Ur + 3072, L1, R1);
    lspd_stats<<<128, 256, 0, stream>>>(L1, R1, part2);
    lspd_fold2<<<1, 256, 0, stream>>>(part2, bng + 32, bnb + 32, Wd + 1024, bd + 32, Wdp, bdp);
    lspd_final<<<512, 512, 0, stream>>>(L1, R1, Wdp, bdp, dg + 32, db + 32, Wf, bf, out);
}

// Round 5
// 881.228 us; speedup vs baseline: 1.0721x; 1.0683x over previous
//
#include <hip/hip_runtime.h>

// LSPD_43404939493531: bidirectional 2-layer GRU (B=512,T=512,U=32) + BN folds + dense head.
// R5: (a) amdgpu_waves_per_eu(1,1) on GRU kernels -> full 512-VGPR budget (launch_bounds(64,1)
//     was only a minimum; allocator stuck at 80 VGPRs in R1-R4). (b) batch all ds_bpermute ops
//     into hk[]/xk[] arrays BEFORE the FMA chains (R4 evidence: both GRUs ~1790 cyc/step ==
//     16 serialized bperm->wait->fma round trips). (c) 2-deep rotation for gru1 x-stream and
//     gru0 idx-stream so global-load latency stays off the shortened chain.

#define Bsz 512
#define Tsz 512

__device__ __forceinline__ float sigmoid_f(float x) {
    return __builtin_amdgcn_rcpf(1.0f + __expf(-x));
}
__device__ __forceinline__ float bperm_f(int addr, float v) {
    return __int_as_float(__builtin_amdgcn_ds_bpermute(addr, __float_as_int(v)));
}

// ---------------- K1: argmax over D=128, one wave per (b,t), t-fastest ----------------
__global__ __launch_bounds__(256) void lspd_argmax(const float* __restrict__ x, int* __restrict__ idxT)
{
    int wv = threadIdx.x >> 6, lane = threadIdx.x & 63;
    long p = (long)blockIdx.x * 4 + wv;           // p = b*512 + t
    const float* xp = x + p * 128;
    float v0 = xp[lane];      int i0 = lane;
    float v1 = xp[64 + lane]; int i1 = 64 + lane;
    if (v1 > v0) { v0 = v1; i0 = i1; }            // ties keep lower index (first occurrence)
#pragma unroll
    for (int d = 1; d < 64; d <<= 1) {
        float ov = __shfl_xor(v0, d, 64);
        int   oi = __shfl_xor(i0, d, 64);
        if (ov > v0 || (ov == v0 && oi < i0)) { v0 = ov; i0 = oi; }
    }
    if (lane == 0) idxT[p] = i0;
}

// ---------------- K0: layer-0 input tables tab[i][g] = (emb@W0)[i][g] + b0_in[g] ----------------
__global__ __launch_bounds__(256) void lspd_tab(
    const float* __restrict__ emb, const float* __restrict__ Wl, const float* __restrict__ bl,
    const float* __restrict__ Wr, const float* __restrict__ br,
    float* __restrict__ tabL, float* __restrict__ tabR)
{
    int flat = blockIdx.x * 256 + threadIdx.x;    // 0..24575
    int dir = flat / 12288;
    int r = flat % 12288;
    int i = r / 96, g = r % 96;
    const float* W  = dir ? Wr : Wl;              // layer 0 at base
    const float* bb = dir ? br : bl;              // b[0][0] input bias at base
    float acc = bb[g];
#pragma unroll
    for (int k = 0; k < 32; ++k) acc = fmaf(emb[i * 32 + k], W[k * 96 + g], acc);
    (dir ? tabR : tabL)[r] = acc;
}

// ---------------- K2: layer-0 GRU, 1 row per wave64, both directions in one grid ----------------
__global__ __launch_bounds__(64)
__attribute__((amdgpu_waves_per_eu(1, 1)))
void lspd_gru0(
    const int* __restrict__ idxT, const float* __restrict__ tabL, const float* __restrict__ tabR,
    const float* __restrict__ Ul, const float* __restrict__ Ur,
    const float* __restrict__ bl, const float* __restrict__ br,
    float* __restrict__ Lout, float* __restrict__ Rout)
{
    int wid = blockIdx.x;
    int dir = wid >> 9;
    int b = wid & 511;
    int lane = threadIdx.x;
    int half = lane >> 5, c = lane & 31;
    const float* U    = dir ? Ur : Ul;
    const float* tab  = dir ? tabR : tabL;
    const float* brec = (dir ? br : bl) + 96;     // layer-0 recurrent bias b[0][1]
    float* out        = dir ? Rout : Lout;

    float u0[16], u1[16], u2[16];
#pragma unroll
    for (int j = 0; j < 16; ++j) {
        int k = half * 16 + j;
        u0[j] = U[k * 96 + c];
        u1[j] = U[k * 96 + 32 + c];
        u2[j] = U[k * 96 + 64 + c];
    }
    float bZ = half ? 0.f : brec[c];
    float bR = half ? 0.f : brec[32 + c];
    float bH = half ? 0.f : brec[64 + c];
#pragma unroll
    for (int j = 0; j < 16; ++j) {
        asm volatile("" : "+v"(u0[j]), "+v"(u1[j]), "+v"(u2[j]));
    }
    asm volatile("" : "+v"(bZ), "+v"(bR), "+v"(bH));
    int axor = (lane ^ 32) << 2;
    int hb = half << 6;                            // source lanes half*16 + j

    const int* idxrow = idxT + (long)b * Tsz;
    if (lane < 32) out[(((long)(dir ? Tsz - 1 : 0)) * Bsz + b) * 32 + c] = 0.f;  // boundary zero

#define TT0(s) (dir ? (Tsz - 2 - (s)) : (1 + (s)))
    long ob = ((long)TT0(0) * Bsz + b) * 32 + c;
    long ostride = (long)(dir ? -1 : 1) * Bsz * 32;

    // gi(s) resident; id1 = idx for step s+1 already loaded (2-deep idx stream)
    float giz, gir, gih;
    { int i0 = idxrow[TT0(0)]; giz = tab[i0 * 96 + c]; gir = tab[i0 * 96 + 32 + c]; gih = tab[i0 * 96 + 64 + c]; }
    int id1 = idxrow[TT0(1)];
    float h = 0.f;

    for (int s = 0; s < Tsz - 1; ++s) {
        float cz = giz, cr = gir, ch = gih;
        // gather gi(s+1) from the already-resident id1; refill id1 with idx(s+2)
        giz = tab[id1 * 96 + c];
        gir = tab[id1 * 96 + 32 + c];
        gih = tab[id1 * 96 + 64 + c];
        int t2 = s + 2; if (t2 > Tsz - 2) t2 = Tsz - 2;
        id1 = idxrow[TT0(t2)];

        // batch all h-broadcasts (independent) ahead of the FMA chains
        float hk[16];
#pragma unroll
        for (int j = 0; j < 16; ++j) hk[j] = bperm_f(hb + 4 * j, h);

        float az = bZ, ar = bR, ah = bH;
#pragma unroll
        for (int j = 0; j < 16; ++j) {
            az = fmaf(hk[j], u0[j], az);
            ar = fmaf(hk[j], u1[j], ar);
            ah = fmaf(hk[j], u2[j], ah);
        }
        float azx = bperm_f(axor, az);
        float arx = bperm_f(axor, ar);
        float ahx = bperm_f(axor, ah);
        az += azx; ar += arx; ah += ahx;
        float z = sigmoid_f(az + cz);
        float r = sigmoid_f(ar + cr);
        float hh = fmaxf(0.f, fmaf(r, ah, ch));
        h = hh + z * (h - hh);
        if (lane < 32) out[ob] = h;
        ob += ostride;
    }
#undef TT0
}

// ---------------- K3/K5: per-channel sum & sumsq of (L+R) ----------------
__global__ __launch_bounds__(256) void lspd_stats(
    const float* __restrict__ A, const float* __restrict__ Bv, float* __restrict__ part)
{
    __shared__ float sS[256], sQ[256];
    int tid = threadIdx.x;
    size_t base = (size_t)blockIdx.x * 65536 + tid;
    float s = 0.f, q = 0.f;
    for (int i = 0; i < 256; ++i) {
        size_t ix = base + (size_t)i * 256;
        float v = A[ix] + Bv[ix];
        s += v; q = fmaf(v, v, q);
    }
    sS[tid] = s; sQ[tid] = q;
    __syncthreads();
    if (tid < 32) {
        float S = 0.f, Q = 0.f;
        for (int j = 0; j < 8; ++j) { S += sS[tid + 32 * j]; Q += sQ[tid + 32 * j]; }
        part[blockIdx.x * 64 + tid] = S;
        part[blockIdx.x * 64 + 32 + tid] = Q;
    }
}

// ---------------- K3b: fold layer-0 BN into layer-1 input weights ----------------
__global__ __launch_bounds__(256) void lspd_fold1(
    const float* __restrict__ part, const float* __restrict__ g0, const float* __restrict__ be0,
    const float* __restrict__ Wl, const float* __restrict__ Wr,
    const float* __restrict__ bl, const float* __restrict__ br,
    float* __restrict__ WpL, float* __restrict__ WpR,
    float* __restrict__ b4L, float* __restrict__ b4R)
{
    __shared__ float sc[32], tc[32];
    int tid = threadIdx.x;
    if (tid < 32) {
        float S = 0.f, Q = 0.f;
        for (int p = 0; p < 128; ++p) { S += part[p * 64 + tid]; Q += part[p * 64 + 32 + tid]; }
        const float invN = 1.0f / 262144.0f;
        float m = S * invN;
        float v = Q * invN - m * m;
        float s = g0[tid] * __builtin_amdgcn_rsqf(v + 1e-3f);
        sc[tid] = s; tc[tid] = be0[tid] - s * m;
    }
    __syncthreads();
    for (int idx = tid; idx < 6144; idx += 256) {
        int dir = idx / 3072, e = idx % 3072, k = e / 96, g = e % 96;
        const float* W1 = (dir ? Wr : Wl) + 3072;      // layer 1
        (dir ? WpR : WpL)[e] = sc[k] * W1[k * 96 + g];
    }
    {
        int idx = tid;                                  // 256 entries exactly
        int dir = idx >> 7, slot = idx & 127, sub = slot >> 5, cc = slot & 31;
        const float* bb = (dir ? br : bl) + 192;        // layer-1: [0..95]=input, [96..191]=recurrent
        const float* W1 = (dir ? Wr : Wl) + 3072;
        float r;
        if (sub == 2) {
            r = bb[96 + 64 + cc];                       // rh: recurrent h-bias only
        } else {
            int g = (sub == 3) ? (64 + cc) : (sub * 32 + cc);
            float acc = bb[g];                          // input bias
            for (int k = 0; k < 32; ++k) acc = fmaf(tc[k], W1[k * 96 + g], acc);
            if (sub < 2) acc += bb[96 + g];             // z,r: + recurrent bias
            r = acc;
        }
        (dir ? b4R : b4L)[slot] = r;
    }
}

// ---------------- K4: layer-1 GRU with on-the-fly folded input projection ----------------
__global__ __launch_bounds__(64)
__attribute__((amdgpu_waves_per_eu(1, 1)))
void lspd_gru1(
    const float* __restrict__ L0, const float* __restrict__ R0,
    const float* __restrict__ WpL, const float* __restrict__ WpR,
    const float* __restrict__ b4L, const float* __restrict__ b4R,
    const float* __restrict__ Ul1, const float* __restrict__ Ur1,
    float* __restrict__ Lout, float* __restrict__ Rout)
{
    int wid = blockIdx.x;
    int dir = wid >> 9;
    int b = wid & 511;
    int lane = threadIdx.x;
    int half = lane >> 5, c = lane & 31;
    const float* U  = dir ? Ur1 : Ul1;
    const float* Wp = dir ? WpR : WpL;
    const float* b4 = dir ? b4R : b4L;
    float* out      = dir ? Rout : Lout;

    float u0[16], u1[16], u2[16], w0[16], w1[16], w2[16];
#pragma unroll
    for (int j = 0; j < 16; ++j) {
        int k = half * 16 + j;
        u0[j] = U[k * 96 + c];
        u1[j] = U[k * 96 + 32 + c];
        u2[j] = U[k * 96 + 64 + c];
        w0[j] = Wp[k * 96 + c];
        w1[j] = Wp[k * 96 + 32 + c];
        w2[j] = Wp[k * 96 + 64 + c];
    }
    float bZ = half ? 0.f : b4[c];
    float bR = half ? 0.f : b4[32 + c];
    float bH = half ? 0.f : b4[64 + c];   // recurrent-h bias
    float bI = half ? 0.f : b4[96 + c];   // input-h bias (folded)
#pragma unroll
    for (int j = 0; j < 16; ++j) {
        asm volatile("" : "+v"(u0[j]), "+v"(u1[j]), "+v"(u2[j]));
        asm volatile("" : "+v"(w0[j]), "+v"(w1[j]), "+v"(w2[j]));
    }
    asm volatile("" : "+v"(bZ), "+v"(bR), "+v"(bH), "+v"(bI));
    int axor = (lane ^ 32) << 2;
    int hb = half << 6;

    if (lane < 32) out[(((long)(dir ? Tsz - 1 : 0)) * Bsz + b) * 32 + c] = 0.f;

#define XADDR(s) (((long)(dir ? (Tsz - 2 - (s)) : (1 + (s))) * Bsz + b) * 32 + c)
    long rb = XADDR(0);
    long stride = (long)(dir ? -1 : 1) * Bsz * 32;

    // 2-deep x pipeline: (xl0,xr0) = x(s), (xl1,xr1) = x(s+1)
    float xl0 = L0[XADDR(0)], xr0 = R0[XADDR(0)];
    float xl1 = L0[XADDR(1)], xr1 = R0[XADDR(1)];
    float h = 0.f;

    for (int s = 0; s < Tsz - 1; ++s) {
        float x = xl0 + xr0;
        xl0 = xl1; xr0 = xr1;
        int t2 = s + 2; if (t2 > Tsz - 2) t2 = Tsz - 2;
        long a2 = XADDR(t2);
        xl1 = L0[a2]; xr1 = R0[a2];

        // batch all 32 broadcasts (independent) ahead of the FMA chains
        float xk[16], hk[16];
#pragma unroll
        for (int j = 0; j < 16; ++j) xk[j] = bperm_f(hb + 4 * j, x);
#pragma unroll
        for (int j = 0; j < 16; ++j) hk[j] = bperm_f(hb + 4 * j, h);

        float az = bZ, ar = bR, ah = bH, ai = bI;
#pragma unroll
        for (int j = 0; j < 16; ++j) {
            az = fmaf(xk[j], w0[j], az);
            ar = fmaf(xk[j], w1[j], ar);
            ai = fmaf(xk[j], w2[j], ai);
        }
#pragma unroll
        for (int j = 0; j < 16; ++j) {
            az = fmaf(hk[j], u0[j], az);
            ar = fmaf(hk[j], u1[j], ar);
            ah = fmaf(hk[j], u2[j], ah);
        }
        float azx = bperm_f(axor, az);
        float arx = bperm_f(axor, ar);
        float ahx = bperm_f(axor, ah);
        float aix = bperm_f(axor, ai);
        az += azx; ar += arx; ah += ahx; ai += aix;
        float z = sigmoid_f(az);
        float r = sigmoid_f(ar);
        float hh = fmaxf(0.f, fmaf(r, ah, ai));
        h = hh + z * (h - hh);
        if (lane < 32) out[rb] = h;
        rb += stride;
    }
#undef XADDR
}

// ---------------- K5b: fold layer-1 BN into dense-1 weights ----------------
__global__ __launch_bounds__(256) void lspd_fold2(
    const float* __restrict__ part, const float* __restrict__ g1, const float* __restrict__ be1,
    const float* __restrict__ Wd1, const float* __restrict__ bd1,
    float* __restrict__ Wdp, float* __restrict__ bdp)
{
    __shared__ float sc[32], tc[32];
    int tid = threadIdx.x;
    if (tid < 32) {
        float S = 0.f, Q = 0.f;
        for (int p = 0; p < 128; ++p) { S += part[p * 64 + tid]; Q += part[p * 64 + 32 + tid]; }
        const float invN = 1.0f / 262144.0f;
        float m = S * invN;
        float v = Q * invN - m * m;
        float s = g1[tid] * __builtin_amdgcn_rsqf(v + 1e-3f);
        sc[tid] = s; tc[tid] = be1[tid] - s * m;
    }
    __syncthreads();
    for (int idx = tid; idx < 1024; idx += 256) {
        int k = idx >> 5;
        Wdp[idx] = sc[k] * Wd1[idx];
    }
    if (tid < 32) {
        float acc = bd1[tid];
        for (int k = 0; k < 32; ++k) acc = fmaf(tc[k], Wd1[k * 32 + tid], acc);
        bdp[tid] = acc;
    }
}

// ---------------- K6: dense + per-t batch BN + classifier + softmax; one block per t ----------------
__global__ __launch_bounds__(512) void lspd_final(
    const float* __restrict__ L1a, const float* __restrict__ R1a,
    const float* __restrict__ Wdp, const float* __restrict__ bdp,
    const float* __restrict__ dg, const float* __restrict__ db,
    const float* __restrict__ Wf, const float* __restrict__ bfv,
    float* __restrict__ outp)
{
    __shared__ alignas(16) float sW[1024];
    __shared__ float sb[32], sWf[352], sbf[16], sS[32], sT[32];
    __shared__ float redS[8][32], redQ[8][32];
    int tid = threadIdx.x, t = blockIdx.x;
    for (int i = tid; i < 1024; i += 512) sW[i] = Wdp[i];
    if (tid < 32)  sb[tid] = bdp[tid];
    if (tid < 352) sWf[tid] = Wf[tid];
    if (tid < 11)  sbf[tid] = bfv[tid];
    __syncthreads();

    size_t base = ((size_t)t * Bsz + tid) * 32;
    float xv[32];
#pragma unroll
    for (int c2 = 0; c2 < 32; c2 += 4) {
        float4 a = *(const float4*)(L1a + base + c2);
        float4 b = *(const float4*)(R1a + base + c2);
        xv[c2 + 0] = a.x + b.x; xv[c2 + 1] = a.y + b.y;
        xv[c2 + 2] = a.z + b.z; xv[c2 + 3] = a.w + b.w;
    }
    float o[32];
#pragma unroll
    for (int g = 0; g < 32; ++g) o[g] = sb[g];
#pragma unroll
    for (int k = 0; k < 32; ++k) {
        float xk = xv[k];
#pragma unroll
        for (int g4 = 0; g4 < 8; ++g4) {
            float4 w = *(const float4*)(sW + k * 32 + g4 * 4);   // same-address LDS broadcast
            o[g4 * 4 + 0] = fmaf(xk, w.x, o[g4 * 4 + 0]);
            o[g4 * 4 + 1] = fmaf(xk, w.y, o[g4 * 4 + 1]);
            o[g4 * 4 + 2] = fmaf(xk, w.z, o[g4 * 4 + 2]);
            o[g4 * 4 + 3] = fmaf(xk, w.w, o[g4 * 4 + 3]);
        }
    }
#pragma unroll
    for (int g = 0; g < 32; ++g) o[g] = fmaxf(o[g], 0.f);

    // per-(t,channel) stats over batch (within block)
    int wv = tid >> 6, lane = tid & 63;
    for (int g = 0; g < 32; ++g) {
        float s = o[g], q = o[g] * o[g];
        for (int d = 1; d < 64; d <<= 1) {
            s += __shfl_xor(s, d, 64);
            q += __shfl_xor(q, d, 64);
        }
        if (lane == 0) { redS[wv][g] = s; redQ[wv][g] = q; }
    }
    __syncthreads();
    if (tid < 32) {
        float S = 0.f, Q = 0.f;
        for (int w2 = 0; w2 < 8; ++w2) { S += redS[w2][tid]; Q += redQ[w2][tid]; }
        float m = S * (1.0f / 512.0f);
        float v = Q * (1.0f / 512.0f) - m * m;
        float s = dg[tid] * __builtin_amdgcn_rsqf(v + 1e-3f);
        sS[tid] = s; sT[tid] = db[tid] - s * m;
    }
    __syncthreads();

    float lg[11];
#pragma unroll
    for (int n = 0; n < 11; ++n) lg[n] = sbf[n];
#pragma unroll
    for (int g = 0; g < 32; ++g) {
        float no = fmaf(o[g], sS[g], sT[g]);
#pragma unroll
        for (int n = 0; n < 11; ++n) lg[n] = fmaf(no, sWf[g * 11 + n], lg[n]);
    }
    float mx = lg[0];
#pragma unroll
    for (int n = 1; n < 11; ++n) mx = fmaxf(mx, lg[n]);
    float sum = 0.f;
#pragma unroll
    for (int n = 0; n < 11; ++n) { lg[n] = __expf(lg[n] - mx); sum += lg[n]; }
    float inv = __builtin_amdgcn_rcpf(sum);
    float* op = outp + ((size_t)tid * Tsz + t) * 11;
#pragma unroll
    for (int n = 0; n < 11; ++n) op[n] = lg[n] * inv;
}

extern "C" void kernel_launch(void* const* d_in, const int* in_sizes, int n_in,
                              void* d_out, int out_size, void* d_ws, size_t ws_size,
                              hipStream_t stream)
{
    (void)in_sizes; (void)n_in; (void)out_size; (void)ws_size;
    const float* x   = (const float*)d_in[0];
    const float* emb = (const float*)d_in[1];
    const float* Wl  = (const float*)d_in[2];
    const float* Ul  = (const float*)d_in[3];
    const float* bl  = (const float*)d_in[4];
    const float* Wr  = (const float*)d_in[5];
    const float* Ur  = (const float*)d_in[6];
    const float* br  = (const float*)d_in[7];
    const float* bng = (const float*)d_in[8];
    const float* bnb = (const float*)d_in[9];
    const float* Wd  = (const float*)d_in[10];
    const float* bd  = (const float*)d_in[11];
    const float* dg  = (const float*)d_in[12];
    const float* db  = (const float*)d_in[13];
    const float* Wf  = (const float*)d_in[14];
    const float* bf  = (const float*)d_in[15];
    float* out = (float*)d_out;

    float* ws = (float*)d_ws;
    float* L0 = ws;
    float* R0 = L0 + 8388608;
    float* L1 = R0 + 8388608;
    float* R1 = L1 + 8388608;
    float* rest = R1 + 8388608;
    int* idxT   = (int*)rest;            // 262144 ints
    float* tabL = rest + 262144;
    float* tabR = tabL + 12288;
    float* part1 = tabR + 12288;         // 8192
    float* part2 = part1 + 8192;         // 8192
    float* WpL = part2 + 8192;           // 3072
    float* WpR = WpL + 3072;
    float* b4L = WpR + 3072;             // 128
    float* b4R = b4L + 128;
    float* Wdp = b4R + 128;              // 1024
    float* bdp = Wdp + 1024;             // 32

    lspd_argmax<<<65536, 256, 0, stream>>>(x, idxT);
    lspd_tab<<<96, 256, 0, stream>>>(emb, Wl, bl, Wr, br, tabL, tabR);
    lspd_gru0<<<1024, 64, 0, stream>>>(idxT, tabL, tabR, Ul, Ur, bl, br, L0, R0);
    lspd_stats<<<128, 256, 0, stream>>>(L0, R0, part1);
    lspd_fold1<<<1, 256, 0, stream>>>(part1, bng, bnb, Wl, Wr, bl, br, WpL, WpR, b4L, b4R);
    lspd_gru1<<<1024, 64, 0, stream>>>(L0, R0, WpL, WpR, b4L, b4R, Ul + 3072, Ur + 3072, L1, R1);
    lspd_stats<<<128, 256, 0, stream>>>(L1, R1, part2);
    lspd_fold2<<<1, 256, 0, stream>>>(part2, bng + 32, bnb + 32, Wd + 1024, bd + 32, Wdp, bdp);
    lspd_final<<<512, 512, 0, stream>>>(L1, R1, Wdp, bdp, dg + 32, db + 32, Wf, bf, out);
}